// Round 2
// baseline (427.393 us; speedup 1.0000x reference)
//
#include <hip/hip_runtime.h>

#define N_NODES 100000
#define N_EDGES 3200000
#define D_NODE 128
#define D_EDGE 16

// ---------------------------------------------------------------------------
// Zero the R replica accumulators in workspace (re-poisoned 0xAA each call).
// ---------------------------------------------------------------------------
__global__ void tmp_zero_ws(float4* __restrict__ ws, int n4) {
    int i = blockIdx.x * blockDim.x + threadIdx.x;
    if (i < n4) ws[i] = make_float4(0.f, 0.f, 0.f, 0.f);
}

// ---------------------------------------------------------------------------
// Edge scatter into replicated accumulators: replica chosen per-wave so that
// the 3.2M atomics spread over R*6250 cachelines instead of 6250.
// ---------------------------------------------------------------------------
__global__ void tmp_edge_scatter_rep(const float* __restrict__ nodes,
                                     const float* __restrict__ edges,
                                     const int*   __restrict__ senders,
                                     const int*   __restrict__ receivers,
                                     const float* __restrict__ w_node,
                                     const float* __restrict__ w_edge,
                                     float* __restrict__ ws, int rmask) {
    const float wn = w_node[0];
    const float we = w_edge[0];
    int t = blockIdx.x * blockDim.x + threadIdx.x;
    int base = t * 4;
    if (base >= N_EDGES) return;
    // per-wave replica: all 64 lanes of a wave hit the same replica copy
    float* dst = ws + (size_t)((t >> 6) & rmask) * N_NODES;
    if (base + 3 < N_EDGES) {
        int4 s = *(const int4*)(senders + base);
        int4 r = *(const int4*)(receivers + base);
        float e0 = edges[(size_t)(base + 0) * D_EDGE];
        float e1 = edges[(size_t)(base + 1) * D_EDGE];
        float e2 = edges[(size_t)(base + 2) * D_EDGE];
        float e3 = edges[(size_t)(base + 3) * D_EDGE];
        float m0 = we * e0 + wn * nodes[(size_t)s.x * D_NODE];
        float m1 = we * e1 + wn * nodes[(size_t)s.y * D_NODE];
        float m2 = we * e2 + wn * nodes[(size_t)s.z * D_NODE];
        float m3 = we * e3 + wn * nodes[(size_t)s.w * D_NODE];
        atomicAdd(&dst[r.x], m0);
        atomicAdd(&dst[r.y], m1);
        atomicAdd(&dst[r.z], m2);
        atomicAdd(&dst[r.w], m3);
    } else {
        for (int e = base; e < N_EDGES; ++e) {
            float m = we * edges[(size_t)e * D_EDGE]
                    + wn * nodes[(size_t)senders[e] * D_NODE];
            atomicAdd(&dst[receivers[e]], m);
        }
    }
}

// ---------------------------------------------------------------------------
// Final: out[i] = w_node*nodes[i,0] + b_node + sum_r ws[r][i]
// ---------------------------------------------------------------------------
__global__ void tmp_reduce_out(const float* __restrict__ nodes,
                               const float* __restrict__ ws,
                               const float* __restrict__ w_node,
                               const float* __restrict__ b_node,
                               float* __restrict__ out, int nrep) {
    int i = blockIdx.x * blockDim.x + threadIdx.x;
    if (i >= N_NODES) return;
    float s = w_node[0] * nodes[(size_t)i * D_NODE] + b_node[0];
    for (int r = 0; r < nrep; ++r) s += ws[(size_t)r * N_NODES + i];
    out[i] = s;
}

// ---------------------------------------------------------------------------
// Fallback (tiny workspace): direct atomics into out, as in round 1.
// ---------------------------------------------------------------------------
__global__ void tmp_init_out(const float* __restrict__ nodes,
                             const float* __restrict__ w_node,
                             const float* __restrict__ b_node,
                             float* __restrict__ out) {
    int i = blockIdx.x * blockDim.x + threadIdx.x;
    if (i < N_NODES) out[i] = w_node[0] * nodes[(size_t)i * D_NODE] + b_node[0];
}

__global__ void tmp_edge_scatter_direct(const float* __restrict__ nodes,
                                        const float* __restrict__ edges,
                                        const int*   __restrict__ senders,
                                        const int*   __restrict__ receivers,
                                        const float* __restrict__ w_node,
                                        const float* __restrict__ w_edge,
                                        float* __restrict__ out) {
    const float wn = w_node[0];
    const float we = w_edge[0];
    int base = (blockIdx.x * blockDim.x + threadIdx.x) * 4;
    if (base + 3 < N_EDGES) {
        int4 s = *(const int4*)(senders + base);
        int4 r = *(const int4*)(receivers + base);
        float m0 = we * edges[(size_t)(base + 0) * D_EDGE] + wn * nodes[(size_t)s.x * D_NODE];
        float m1 = we * edges[(size_t)(base + 1) * D_EDGE] + wn * nodes[(size_t)s.y * D_NODE];
        float m2 = we * edges[(size_t)(base + 2) * D_EDGE] + wn * nodes[(size_t)s.z * D_NODE];
        float m3 = we * edges[(size_t)(base + 3) * D_EDGE] + wn * nodes[(size_t)s.w * D_NODE];
        atomicAdd(&out[r.x], m0);
        atomicAdd(&out[r.y], m1);
        atomicAdd(&out[r.z], m2);
        atomicAdd(&out[r.w], m3);
    } else {
        for (int e = base; e < N_EDGES; ++e) {
            float m = we * edges[(size_t)e * D_EDGE] + wn * nodes[(size_t)senders[e] * D_NODE];
            atomicAdd(&out[receivers[e]], m);
        }
    }
}

extern "C" void kernel_launch(void* const* d_in, const int* in_sizes, int n_in,
                              void* d_out, int out_size, void* d_ws, size_t ws_size,
                              hipStream_t stream) {
    const float* nodes     = (const float*)d_in[0];
    const float* edges     = (const float*)d_in[1];
    const int*   senders   = (const int*)d_in[2];
    const int*   receivers = (const int*)d_in[3];
    const float* w_node    = (const float*)d_in[4];
    const float* w_edge    = (const float*)d_in[5];
    const float* b_node    = (const float*)d_in[6];
    float* out = (float*)d_out;
    float* ws  = (float*)d_ws;

    // replica count: largest power of two <= 16 that fits in ws
    int R = 0;
    {
        size_t per = (size_t)N_NODES * sizeof(float);
        if (ws_size >= per) {
            R = 1;
            while (R < 16 && (size_t)(R * 2) * per <= ws_size) R *= 2;
        }
    }

    if (R > 0) {
        {
            int n4 = (R * N_NODES) / 4;  // N_NODES % 4 == 0
            int threads = 256;
            tmp_zero_ws<<<(n4 + threads - 1) / threads, threads, 0, stream>>>(
                (float4*)ws, n4);
        }
        {
            int threads = 256;
            int n_thr = N_EDGES / 4;
            tmp_edge_scatter_rep<<<(n_thr + threads - 1) / threads, threads, 0, stream>>>(
                nodes, edges, senders, receivers, w_node, w_edge, ws, R - 1);
        }
        {
            int threads = 256;
            tmp_reduce_out<<<(N_NODES + threads - 1) / threads, threads, 0, stream>>>(
                nodes, ws, w_node, b_node, out, R);
        }
    } else {
        int threads = 256;
        tmp_init_out<<<(N_NODES + threads - 1) / threads, threads, 0, stream>>>(
            nodes, w_node, b_node, out);
        int n_thr = N_EDGES / 4;
        tmp_edge_scatter_direct<<<(n_thr + threads - 1) / threads, threads, 0, stream>>>(
            nodes, edges, senders, receivers, w_node, w_edge, out);
    }
}

// Round 3
// 388.542 us; speedup vs baseline: 1.1000x; 1.1000x over previous
//
#include <hip/hip_runtime.h>

#define N_NODES 100000
#define N_EDGES 3200000
#define D_NODE 128
#define D_EDGE 16

#define RANGE_BITS 14
#define RANGE_SIZE (1 << RANGE_BITS)          // 16384 nodes per range, 64 KB LDS
#define RANGE_MASK (RANGE_SIZE - 1)
#define N_RANGES 7                            // 7*16384 = 114688 >= 100000

// ws layout (in floats)
#define WS_X_OFF    0                         // 100000 floats (node column)
#define WS_MSG_OFF  102400                    // 3.2M floats (messages)
#define WS_PART_OFF (102400 + N_EDGES)        // partials: N_RANGES*NB*RANGE_SIZE

// ---------------------------------------------------------------------------
// K0: x[i] = nodes[i, 0]  (compact the gathered column so K1's gather is
// L2-resident: 400 KB instead of a 51 MB span)
// ---------------------------------------------------------------------------
__global__ void tmp_k0_extract(const float* __restrict__ nodes,
                               float* __restrict__ x) {
    int i = blockIdx.x * blockDim.x + threadIdx.x;
    if (i < N_NODES) x[i] = nodes[(size_t)i * D_NODE];
}

// ---------------------------------------------------------------------------
// K1: msg[e] = w_edge*edges[e,0] + w_node*x[senders[e]]   (coalesced store)
// ---------------------------------------------------------------------------
__global__ void tmp_k1_messages(const float* __restrict__ x,
                                const float* __restrict__ edges,
                                const int*   __restrict__ senders,
                                const float* __restrict__ w_node,
                                const float* __restrict__ w_edge,
                                float* __restrict__ msg) {
    const float wn = w_node[0];
    const float we = w_edge[0];
    int base = (blockIdx.x * blockDim.x + threadIdx.x) * 4;
    if (base >= N_EDGES) return;
    int4 s = *(const int4*)(senders + base);
    float4 m;
    m.x = we * edges[(size_t)(base + 0) * D_EDGE] + wn * x[s.x];
    m.y = we * edges[(size_t)(base + 1) * D_EDGE] + wn * x[s.y];
    m.z = we * edges[(size_t)(base + 2) * D_EDGE] + wn * x[s.z];
    m.w = we * edges[(size_t)(base + 3) * D_EDGE] + wn * x[s.w];
    *(float4*)(msg + base) = m;
}

// ---------------------------------------------------------------------------
// K2: atomic-free segment sum. blockIdx.y = node range (16384 nodes), LDS
// accumulator; blockIdx.x = edge slice. recv+msg (25.6 MB) stay LLC-resident
// across the 7 range scans. Each block writes its FULL partial slice, so no
// workspace pre-zeroing is needed.
// ---------------------------------------------------------------------------
__global__ void tmp_k2_accum(const float* __restrict__ msg,
                             const int*   __restrict__ receivers,
                             float* __restrict__ partials, int nb) {
    extern __shared__ float acc[];                  // RANGE_SIZE floats = 64 KB
    const int range = blockIdx.y;
    const int slice = blockIdx.x;

    for (int i = threadIdx.x; i < RANGE_SIZE; i += blockDim.x) acc[i] = 0.f;
    __syncthreads();

    int chunk = (N_EDGES + nb - 1) / nb;
    chunk = (chunk + 3) & ~3;                       // multiple of 4
    int start = slice * chunk;
    int end = start + chunk; if (end > N_EDGES) end = N_EDGES;

    for (int e = start + (int)threadIdx.x * 4; e < end; e += (int)blockDim.x * 4) {
        int4 r = *(const int4*)(receivers + e);
        float4 m = *(const float4*)(msg + e);
        if ((r.x >> RANGE_BITS) == range) atomicAdd(&acc[r.x & RANGE_MASK], m.x);
        if ((r.y >> RANGE_BITS) == range) atomicAdd(&acc[r.y & RANGE_MASK], m.y);
        if ((r.z >> RANGE_BITS) == range) atomicAdd(&acc[r.z & RANGE_MASK], m.z);
        if ((r.w >> RANGE_BITS) == range) atomicAdd(&acc[r.w & RANGE_MASK], m.w);
    }
    __syncthreads();

    float* dst = partials + ((size_t)(range * nb + slice) << RANGE_BITS);
    for (int i = threadIdx.x; i < RANGE_SIZE; i += blockDim.x) dst[i] = acc[i];
}

// ---------------------------------------------------------------------------
// K3: out[i] = w_node*x[i] + b_node + sum_b partials[range(i)][b][local(i)]
// ---------------------------------------------------------------------------
__global__ void tmp_k3_reduce(const float* __restrict__ x,
                              const float* __restrict__ partials,
                              const float* __restrict__ w_node,
                              const float* __restrict__ b_node,
                              float* __restrict__ out, int nb) {
    int i = blockIdx.x * blockDim.x + threadIdx.x;
    if (i >= N_NODES) return;
    int range = i >> RANGE_BITS;
    int local = i & RANGE_MASK;
    float s = w_node[0] * x[i] + b_node[0];
    const float* p = partials + ((size_t)(range * nb) << RANGE_BITS) + local;
    for (int b = 0; b < nb; ++b) s += p[(size_t)b << RANGE_BITS];
    out[i] = s;
}

// ---------------------------------------------------------------------------
// Fallback (workspace too small): round-1 direct atomic path.
// ---------------------------------------------------------------------------
__global__ void tmp_init_out(const float* __restrict__ nodes,
                             const float* __restrict__ w_node,
                             const float* __restrict__ b_node,
                             float* __restrict__ out) {
    int i = blockIdx.x * blockDim.x + threadIdx.x;
    if (i < N_NODES) out[i] = w_node[0] * nodes[(size_t)i * D_NODE] + b_node[0];
}

__global__ void tmp_edge_scatter_direct(const float* __restrict__ nodes,
                                        const float* __restrict__ edges,
                                        const int*   __restrict__ senders,
                                        const int*   __restrict__ receivers,
                                        const float* __restrict__ w_node,
                                        const float* __restrict__ w_edge,
                                        float* __restrict__ out) {
    const float wn = w_node[0];
    const float we = w_edge[0];
    int base = (blockIdx.x * blockDim.x + threadIdx.x) * 4;
    if (base + 3 < N_EDGES) {
        int4 s = *(const int4*)(senders + base);
        int4 r = *(const int4*)(receivers + base);
        atomicAdd(&out[r.x], we * edges[(size_t)(base + 0) * D_EDGE] + wn * nodes[(size_t)s.x * D_NODE]);
        atomicAdd(&out[r.y], we * edges[(size_t)(base + 1) * D_EDGE] + wn * nodes[(size_t)s.y * D_NODE]);
        atomicAdd(&out[r.z], we * edges[(size_t)(base + 2) * D_EDGE] + wn * nodes[(size_t)s.z * D_NODE]);
        atomicAdd(&out[r.w], we * edges[(size_t)(base + 3) * D_EDGE] + wn * nodes[(size_t)s.w * D_NODE]);
    } else {
        for (int e = base; e < N_EDGES; ++e) {
            atomicAdd(&out[receivers[e]],
                      we * edges[(size_t)e * D_EDGE] + wn * nodes[(size_t)senders[e] * D_NODE]);
        }
    }
}

extern "C" void kernel_launch(void* const* d_in, const int* in_sizes, int n_in,
                              void* d_out, int out_size, void* d_ws, size_t ws_size,
                              hipStream_t stream) {
    const float* nodes     = (const float*)d_in[0];
    const float* edges     = (const float*)d_in[1];
    const int*   senders   = (const int*)d_in[2];
    const int*   receivers = (const int*)d_in[3];
    const float* w_node    = (const float*)d_in[4];
    const float* w_edge    = (const float*)d_in[5];
    const float* b_node    = (const float*)d_in[6];
    float* out = (float*)d_out;
    float* ws  = (float*)d_ws;

    // pick NB (slices per range) by workspace budget
    int nb = 0;
    for (int cand : {64, 48, 32, 16, 8}) {
        size_t need = ((size_t)WS_PART_OFF +
                       (size_t)N_RANGES * cand * RANGE_SIZE) * sizeof(float);
        if (ws_size >= need) { nb = cand; break; }
    }

    if (nb > 0) {
        float* x        = ws + WS_X_OFF;
        float* msg      = ws + WS_MSG_OFF;
        float* partials = ws + WS_PART_OFF;
        int threads = 256;

        tmp_k0_extract<<<(N_NODES + threads - 1) / threads, threads, 0, stream>>>(
            nodes, x);

        int n_thr = N_EDGES / 4;
        tmp_k1_messages<<<(n_thr + threads - 1) / threads, threads, 0, stream>>>(
            x, edges, senders, w_node, w_edge, msg);

        dim3 grid2(nb, N_RANGES);
        tmp_k2_accum<<<grid2, threads, RANGE_SIZE * sizeof(float), stream>>>(
            msg, receivers, partials, nb);

        tmp_k3_reduce<<<(N_NODES + threads - 1) / threads, threads, 0, stream>>>(
            x, partials, w_node, b_node, out, nb);
    } else {
        int threads = 256;
        tmp_init_out<<<(N_NODES + threads - 1) / threads, threads, 0, stream>>>(
            nodes, w_node, b_node, out);
        int n_thr = N_EDGES / 4;
        tmp_edge_scatter_direct<<<(n_thr + threads - 1) / threads, threads, 0, stream>>>(
            nodes, edges, senders, receivers, w_node, w_edge, out);
    }
}